// Round 2
// baseline (98.240 us; speedup 1.0000x reference)
//
#include <hip/hip_runtime.h>
#include <cmath>

#define T_LEN 8192
#define B_ROWS 128
#define ND 360          // MAX_DELAY - MIN_DELAY
#define MIN_DELAY_C 60
#define BLOCK 256       // 4 waves

// Lag-doubling: 1/(1+S) = (1-S)(1+S^2)(1+S^4) / (1-S^8),  S = a1 z^-dA + a2 z^-dB
// -> 3 parallel FIR passes + a recurrence whose min lag is 8*min(dA,dB) >= 488.

__global__ __launch_bounds__(BLOCK) void ks_resonator_kernel(
    const float* __restrict__ excitation,     // (128,1,8192)
    const float* __restrict__ gumbel,         // (360,)
    const float* __restrict__ delay_param,    // (360,)
    const float* __restrict__ feedback_gain,  // (1,)
    const float* __restrict__ refl,           // (2,)
    float* __restrict__ out)                  // (128,1,8192)
{
    __shared__ float bufA[T_LEN];             // 32 KB ping
    __shared__ float bufB[T_LEN];             // 32 KB pong
    __shared__ float red_v[BLOCK];
    __shared__ int   red_i[BLOCK];
    __shared__ float s_a1, s_a2;
    __shared__ int   s_dA, s_dB;
    __shared__ float s_c2[3], s_c4[5], s_c8[9];
    __shared__ int   s_l2[3], s_l4[5], s_l8[9];

    const int tid = threadIdx.x;
    const int row = blockIdx.x;

    // ---- load excitation row into LDS bufA (float4, all 4 waves) ----
    const float4* __restrict__ x4 = (const float4*)(excitation + (size_t)row * T_LEN);
    float4* a4 = (float4*)bufA;
    for (int i = tid; i < T_LEN / 4; i += BLOCK) a4[i] = x4[i];

    // ---- redundant per-block argmax over (delay_param + gumbel), 360 elems ----
    float v = -INFINITY; int idx = 0;
    if (tid < ND) { v = delay_param[tid] + gumbel[tid]; idx = tid; }
    if (tid + BLOCK < ND) {
        float v2 = delay_param[tid + BLOCK] + gumbel[tid + BLOCK];
        if (v2 > v) { v = v2; idx = tid + BLOCK; }   // higher index: strict > only
    }
    red_v[tid] = v; red_i[tid] = idx;
    __syncthreads();
    for (int off = BLOCK / 2; off > 0; off >>= 1) {
        if (tid < off) {
            float v2 = red_v[tid + off]; int i2 = red_i[tid + off];
            float v1 = red_v[tid];       int i1 = red_i[tid];
            // jnp.argmax: first occurrence wins ties
            if (v2 > v1 || (v2 == v1 && i2 < i1)) { red_v[tid] = v2; red_i[tid] = i2; }
        }
        __syncthreads();
    }

    if (tid == 0) {
        int p = red_i[0];
        // rc = tanh(reflection_coeffs); k = resonant_activation(rc, 0) = tanh(rc)
        float k1 = tanhf(tanhf(refl[0]));
        float k2 = tanhf(tanhf(refl[1]));
        float a1 = k1 * (1.0f - k2);
        float a2 = fminf(fmaxf(k2, -0.999f), 0.999f);
        float bound = 0.999f - fabsf(a2);
        a1 = fminf(fmaxf(a1, -bound), bound);
        float fg = feedback_gain[0];
        float g = powf(1.0f / (1.0f + expf(-fg)), 0.45f);
        a1 *= g; a2 *= g;
        int p2 = (p + 1) % ND;           // jnp.roll(one_hot, 1)
        int dA = MIN_DELAY_C + p + 1;    // coeff at 60+p multiplies y[t-1-(60+p)]
        int dB = MIN_DELAY_C + p2 + 1;

        // powers of a1, a2 (no powf: handles a==0 cleanly)
        float p1[9], q2[9];
        p1[0] = 1.0f; q2[0] = 1.0f;
        for (int i = 1; i < 9; ++i) { p1[i] = p1[i-1] * a1; q2[i] = q2[i-1] * a2; }
        const float C2[3] = {1.f, 2.f, 1.f};
        const float C4[5] = {1.f, 4.f, 6.f, 4.f, 1.f};
        const float C8[9] = {1.f, 8.f, 28.f, 56.f, 70.f, 56.f, 28.f, 8.f, 1.f};
        // S^m = sum_i C(m,i) a1^i a2^(m-i) z^-(i*dA + (m-i)*dB)
        for (int i = 0; i < 3; ++i) { s_c2[i] = C2[i] * p1[i] * q2[2-i]; s_l2[i] = i*dA + (2-i)*dB; }
        for (int i = 0; i < 5; ++i) { s_c4[i] = C4[i] * p1[i] * q2[4-i]; s_l4[i] = i*dA + (4-i)*dB; }
        for (int i = 0; i < 9; ++i) { s_c8[i] = C8[i] * p1[i] * q2[8-i]; s_l8[i] = i*dA + (8-i)*dB; }
        s_a1 = a1; s_a2 = a2; s_dA = dA; s_dB = dB;
    }
    __syncthreads();   // also drains the row load into bufA

    const float a1 = s_a1, a2 = s_a2;
    const int dA = s_dA, dB = s_dB;

    // ---- pass 1: bufB = (1 - S) bufA ----
    for (int t = tid; t < T_LEN; t += BLOCK) {
        float acc = bufA[t];
        if (t >= dA) acc -= a1 * bufA[t - dA];
        if (t >= dB) acc -= a2 * bufA[t - dB];
        bufB[t] = acc;
    }
    __syncthreads();

    // ---- pass 2: bufA = (1 + S^2) bufB ----
    {
        float c0 = s_c2[0], c1 = s_c2[1], c2 = s_c2[2];
        int   l0 = s_l2[0], l1 = s_l2[1], l2 = s_l2[2];
        for (int t = tid; t < T_LEN; t += BLOCK) {
            float acc = bufB[t];
            if (t >= l0) acc += c0 * bufB[t - l0];
            if (t >= l1) acc += c1 * bufB[t - l1];
            if (t >= l2) acc += c2 * bufB[t - l2];
            bufA[t] = acc;
        }
    }
    __syncthreads();

    // ---- pass 3: bufB = (1 + S^4) bufA ----
    {
        float c[5]; int l[5];
#pragma unroll
        for (int k = 0; k < 5; ++k) { c[k] = s_c4[k]; l[k] = s_l4[k]; }
        for (int t = tid; t < T_LEN; t += BLOCK) {
            float acc = bufA[t];
#pragma unroll
            for (int k = 0; k < 5; ++k) {
                int s = t - l[k];
                if (s >= 0) acc += c[k] * bufA[s];
            }
            bufB[t] = acc;
        }
    }
    __syncthreads();

    // ---- recurrence: y = w + S^8 y, in-place in bufB; min lag = 8*min(dA,dB) >= 488 ----
    {
        float c[9]; int l[9];
#pragma unroll
        for (int k = 0; k < 9; ++k) { c[k] = s_c8[k]; l[k] = s_l8[k]; }
        const int W = 8 * (dA < dB ? dA : dB);   // safe parallel-chunk width, 488..3360
        for (int pos = 0; pos < T_LEN; pos += W) {
            int end = pos + W; if (end > T_LEN) end = T_LEN;
            for (int j = pos + tid; j < end; j += BLOCK) {
                float acc = bufB[j];
#pragma unroll
                for (int k = 0; k < 9; ++k) {
                    int s = j - l[k];            // s <= pos-1: reads only finished chunks
                    if (s >= 0) acc += c[k] * bufB[s];
                }
                bufB[j] = acc;
            }
            __syncthreads();
        }
    }

    // ---- store (float4, all 4 waves) ----
    float4* __restrict__ o4 = (float4*)(out + (size_t)row * T_LEN);
    const float4* b4 = (const float4*)bufB;
    for (int i = tid; i < T_LEN / 4; i += BLOCK) o4[i] = b4[i];
}

extern "C" void kernel_launch(void* const* d_in, const int* in_sizes, int n_in,
                              void* d_out, int out_size, void* d_ws, size_t ws_size,
                              hipStream_t stream) {
    const float* excitation    = (const float*)d_in[0];
    const float* gumbel        = (const float*)d_in[1];
    const float* delay_param   = (const float*)d_in[2];
    const float* feedback_gain = (const float*)d_in[3];
    const float* refl          = (const float*)d_in[4];
    float* out = (float*)d_out;

    ks_resonator_kernel<<<B_ROWS, BLOCK, 0, stream>>>(
        excitation, gumbel, delay_param, feedback_gain, refl, out);
}

// Round 3
// 78.054 us; speedup vs baseline: 1.2586x; 1.2586x over previous
//
#include <hip/hip_runtime.h>
#include <cmath>

#define T_LEN 8192
#define B_ROWS 128
#define ND 360          // MAX_DELAY - MIN_DELAY
#define MIN_DELAY_C 60
#define BLOCK 256       // 4 waves
#define NCH (T_LEN / BLOCK)   // 32 strided timesteps per thread

// Lag-doubling: 1/(1+S) = (1-S)(1+S^2)(1+S^4) / (1-S^8),  S = a1 z^-dA + a2 z^-dB
// 3 parallel FIR passes + recurrence with min lag 8*min(dA,dB) >= 488.
// This round: ILP-batched LDS reads (boundary/bulk split, 4x unroll) to kill
// the per-read latency serialization that made round 2 run at 40 us.

template<int NT>
__device__ __forceinline__ void fir_pass(const float* __restrict__ src,
                                         float* __restrict__ dst,
                                         const float* __restrict__ sc,
                                         const int* __restrict__ sl,
                                         int maxlag, int tid)
{
    float c[NT]; int l[NT];
#pragma unroll
    for (int j = 0; j < NT; ++j) { c[j] = sc[j]; l[j] = sl[j]; }

    int kStart = (maxlag + BLOCK - 1) / BLOCK;   // uniform: t >= maxlag for all tid
    if (kStart > NCH) kStart = NCH;
    const int kB = NCH - ((NCH - kStart) & ~3);  // bulk count multiple of 4

    // boundary: predicated taps, reads still batched per timestep
    for (int k = 0; k < kB; ++k) {
        const int t = tid + k * BLOCK;
        float r[NT + 1];
        r[0] = src[t];
#pragma unroll
        for (int j = 0; j < NT; ++j) {
            int s = t - l[j];
            r[j + 1] = (s >= 0) ? src[s] : 0.0f;
        }
        float acc = r[0];
#pragma unroll
        for (int j = 0; j < NT; ++j) acc += c[j] * r[j + 1];
        dst[t] = acc;
    }
    // bulk: branch-free, 4 timesteps per group, all reads issued before FMAs
    for (int k = kB; k < NCH; k += 4) {
        float r[4][NT + 1];
#pragma unroll
        for (int u = 0; u < 4; ++u) {
            const int t = tid + (k + u) * BLOCK;
            r[u][0] = src[t];
#pragma unroll
            for (int j = 0; j < NT; ++j) r[u][j + 1] = src[t - l[j]];
        }
#pragma unroll
        for (int u = 0; u < 4; ++u) {
            const int t = tid + (k + u) * BLOCK;
            float acc = r[u][0];
#pragma unroll
            for (int j = 0; j < NT; ++j) acc += c[j] * r[u][j + 1];
            dst[t] = acc;
        }
    }
}

__global__ __launch_bounds__(BLOCK) void ks_resonator_kernel(
    const float* __restrict__ excitation,     // (128,1,8192)
    const float* __restrict__ gumbel,         // (360,)
    const float* __restrict__ delay_param,    // (360,)
    const float* __restrict__ feedback_gain,  // (1,)
    const float* __restrict__ refl,           // (2,)
    float* __restrict__ out)                  // (128,1,8192)
{
    __shared__ float bufA[T_LEN];             // 32 KB ping
    __shared__ float bufB[T_LEN];             // 32 KB pong
    __shared__ float s_c1[2], s_c2[3], s_c4[5], s_c8[9];
    __shared__ int   s_l1[2], s_l2[3], s_l4[5], s_l8[9];
    __shared__ int   s_dA, s_dB;

    const int tid = threadIdx.x;
    const int row = blockIdx.x;

    if (tid < 192) {
        // ---- waves 0-2: load excitation row into LDS (float4) ----
        const float4* __restrict__ x4 = (const float4*)(excitation + (size_t)row * T_LEN);
        float4* a4 = (float4*)bufA;
        for (int i = tid; i < T_LEN / 4; i += 192) a4[i] = x4[i];
    } else {
        // ---- wave 3: argmax over (delay_param + gumbel) via shfl butterfly ----
        const int lane = tid - 192;
        float v = -INFINITY; int idx = 0;
        for (int i = lane; i < ND; i += 64) {
            float w = delay_param[i] + gumbel[i];
            if (w > v) { v = w; idx = i; }     // strict >: first occurrence wins
        }
#pragma unroll
        for (int off = 32; off > 0; off >>= 1) {
            float v2 = __shfl_xor(v, off);
            int   i2 = __shfl_xor(idx, off);
            if (v2 > v || (v2 == v && i2 < idx)) { v = v2; idx = i2; }
        }
        if (lane == 0) {
            const int p = idx;
            // rc = tanh(reflection_coeffs); k = resonant_activation(rc, 0) = tanh(rc)
            float k1 = tanhf(tanhf(refl[0]));
            float k2 = tanhf(tanhf(refl[1]));
            float a1 = k1 * (1.0f - k2);
            float a2 = fminf(fmaxf(k2, -0.999f), 0.999f);
            float bound = 0.999f - fabsf(a2);
            a1 = fminf(fmaxf(a1, -bound), bound);
            float fg = feedback_gain[0];
            float g = powf(1.0f / (1.0f + expf(-fg)), 0.45f);
            a1 *= g; a2 *= g;
            const int p2 = (p + 1) % ND;           // jnp.roll(one_hot, 1)
            const int dA = MIN_DELAY_C + p + 1;    // coeff 60+p multiplies y[t-(61+p)]
            const int dB = MIN_DELAY_C + p2 + 1;

            float p1[9], q2[9];
            p1[0] = 1.0f; q2[0] = 1.0f;
            for (int i = 1; i < 9; ++i) { p1[i] = p1[i-1] * a1; q2[i] = q2[i-1] * a2; }
            const float C2[3] = {1.f, 2.f, 1.f};
            const float C4[5] = {1.f, 4.f, 6.f, 4.f, 1.f};
            const float C8[9] = {1.f, 8.f, 28.f, 56.f, 70.f, 56.f, 28.f, 8.f, 1.f};
            // (1 - S):
            s_c1[0] = -a1; s_l1[0] = dA;
            s_c1[1] = -a2; s_l1[1] = dB;
            // S^m = sum_i C(m,i) a1^i a2^(m-i) z^-(i*dA + (m-i)*dB)
            for (int i = 0; i < 3; ++i) { s_c2[i] = C2[i] * p1[i] * q2[2-i]; s_l2[i] = i*dA + (2-i)*dB; }
            for (int i = 0; i < 5; ++i) { s_c4[i] = C4[i] * p1[i] * q2[4-i]; s_l4[i] = i*dA + (4-i)*dB; }
            for (int i = 0; i < 9; ++i) { s_c8[i] = C8[i] * p1[i] * q2[8-i]; s_l8[i] = i*dA + (8-i)*dB; }
            s_dA = dA; s_dB = dB;
        }
    }
    __syncthreads();   // row loaded + tables ready

    const int dA = s_dA, dB = s_dB;
    const int dmax = (dA > dB) ? dA : dB;

    // ---- pass 1: bufB = (1 - S) bufA ----
    fir_pass<2>(bufA, bufB, s_c1, s_l1, dmax, tid);
    __syncthreads();

    // ---- pass 2: bufA = (1 + S^2) bufB ----
    fir_pass<3>(bufB, bufA, s_c2, s_l2, 2 * dmax, tid);
    __syncthreads();

    // ---- pass 3: bufB = (1 + S^4) bufA ----
    fir_pass<5>(bufA, bufB, s_c4, s_l4, 4 * dmax, tid);
    __syncthreads();

    // ---- recurrence: y = w + S^8 y, in-place in bufB; min lag = 8*min(dA,dB) >= 488 ----
    {
        float c[9]; int l[9];
#pragma unroll
        for (int j = 0; j < 9; ++j) { c[j] = s_c8[j]; l[j] = s_l8[j]; }
        const int dmin = (dA < dB) ? dA : dB;
        const int W  = 8 * dmin;    // safe parallel-chunk width, 488..3360
        const int L8 = 8 * dmax;    // beyond this, no boundary predication needed
        for (int pos = 0; pos < T_LEN; pos += W) {
            int end = pos + W; if (end > T_LEN) end = T_LEN;
            if (pos >= L8) {
                int j = pos + tid;
                for (; j + BLOCK < end; j += 2 * BLOCK) {   // 2x unroll, reads batched
                    float r0[10], r1[10];
                    r0[0] = bufB[j]; r1[0] = bufB[j + BLOCK];
#pragma unroll
                    for (int k = 0; k < 9; ++k) {
                        r0[k + 1] = bufB[j - l[k]];          // all < pos: prior chunks
                        r1[k + 1] = bufB[j + BLOCK - l[k]];
                    }
                    float a0 = r0[0], a1v = r1[0];
#pragma unroll
                    for (int k = 0; k < 9; ++k) { a0 += c[k] * r0[k + 1]; a1v += c[k] * r1[k + 1]; }
                    bufB[j] = a0; bufB[j + BLOCK] = a1v;
                }
                if (j < end) {
                    float r[10]; r[0] = bufB[j];
#pragma unroll
                    for (int k = 0; k < 9; ++k) r[k + 1] = bufB[j - l[k]];
                    float a0 = r[0];
#pragma unroll
                    for (int k = 0; k < 9; ++k) a0 += c[k] * r[k + 1];
                    bufB[j] = a0;
                }
            } else {
                for (int j = pos + tid; j < end; j += BLOCK) {
                    float r[10]; r[0] = bufB[j];
#pragma unroll
                    for (int k = 0; k < 9; ++k) {
                        int s = j - l[k];
                        r[k + 1] = (s >= 0) ? bufB[s] : 0.0f;
                    }
                    float a0 = r[0];
#pragma unroll
                    for (int k = 0; k < 9; ++k) a0 += c[k] * r[k + 1];
                    bufB[j] = a0;
                }
            }
            __syncthreads();
        }
    }

    // ---- store (float4, all 4 waves) ----
    float4* __restrict__ o4 = (float4*)(out + (size_t)row * T_LEN);
    const float4* b4 = (const float4*)bufB;
    for (int i = tid; i < T_LEN / 4; i += BLOCK) o4[i] = b4[i];
}

extern "C" void kernel_launch(void* const* d_in, const int* in_sizes, int n_in,
                              void* d_out, int out_size, void* d_ws, size_t ws_size,
                              hipStream_t stream) {
    const float* excitation    = (const float*)d_in[0];
    const float* gumbel        = (const float*)d_in[1];
    const float* delay_param   = (const float*)d_in[2];
    const float* feedback_gain = (const float*)d_in[3];
    const float* refl          = (const float*)d_in[4];
    float* out = (float*)d_out;

    ks_resonator_kernel<<<B_ROWS, BLOCK, 0, stream>>>(
        excitation, gumbel, delay_param, feedback_gain, refl, out);
}

// Round 5
// 74.480 us; speedup vs baseline: 1.3190x; 1.0480x over previous
//
#include <hip/hip_runtime.h>
#include <cmath>

#define T_LEN 8192
#define B_ROWS 128
#define ND 360          // MAX_DELAY - MIN_DELAY
#define MIN_DELAY_C 60
#define BLOCK 1024      // 16 waves -> 4 waves/SIMD: TLP hides LDS latency
#define GSTRIDE (4 * BLOCK)   // 4096: each thread owns 4 consecutive samples x 2 groups

// Lag-doubling: 1/(1+S) = (1-S)(1+S^2)(1+S^4) / (1-S^8),  S = a1 z^-dA + a2 z^-dB
// 3 parallel FIR passes + recurrence with min lag 8*min(dA,dB) >= 488 (<=17 chunks).
// Round 5 = Round 4 re-run (infra failure, no measurement): BLOCK 256->1024
// (occupancy 1->4 waves/SIMD), 4-consecutive-sample mapping (b128 center/write,
// pairable lagged reads), branch-free clamp masking.

template<int NT, bool MASK>
__device__ __forceinline__ void fir_group(const float* __restrict__ src,
                                          float* __restrict__ dst, int t0,
                                          const float* __restrict__ c,
                                          const int* __restrict__ l)
{
    const float4 x = *(const float4*)&src[t0];
    float r[NT][4];
#pragma unroll
    for (int j = 0; j < NT; ++j) {
#pragma unroll
        for (int e = 0; e < 4; ++e) {
            const int s = t0 + e - l[j];
            if (MASK) {
                const float v = src[(s >= 0) ? s : 0];   // clamped: always issued
                r[j][e] = (s >= 0) ? v : 0.0f;
            } else {
                r[j][e] = src[s];
            }
        }
    }
    float acc[4] = {x.x, x.y, x.z, x.w};
#pragma unroll
    for (int j = 0; j < NT; ++j)
#pragma unroll
        for (int e = 0; e < 4; ++e) acc[e] += c[j] * r[j][e];
    *(float4*)&dst[t0] = make_float4(acc[0], acc[1], acc[2], acc[3]);
}

__global__ __launch_bounds__(BLOCK) void ks_resonator_kernel(
    const float* __restrict__ excitation,     // (128,1,8192)
    const float* __restrict__ gumbel,         // (360,)
    const float* __restrict__ delay_param,    // (360,)
    const float* __restrict__ feedback_gain,  // (1,)
    const float* __restrict__ refl,           // (2,)
    float* __restrict__ out)                  // (128,1,8192)
{
    __shared__ __align__(16) float bufA[T_LEN];   // 32 KB ping
    __shared__ __align__(16) float bufB[T_LEN];   // 32 KB pong
    __shared__ float s_c1[2], s_c2[3], s_c4[5], s_c8[9];
    __shared__ int   s_l1[2], s_l2[3], s_l4[5], s_l8[9];
    __shared__ int   s_dA, s_dB;

    const int tid = threadIdx.x;
    const int row = blockIdx.x;

    if (tid < 960) {
        // ---- waves 0-14: load excitation row into LDS (float4) ----
        const float4* __restrict__ x4 = (const float4*)(excitation + (size_t)row * T_LEN);
        float4* a4 = (float4*)bufA;
        for (int i = tid; i < T_LEN / 4; i += 960) a4[i] = x4[i];
    } else {
        // ---- wave 15: argmax over (delay_param + gumbel) via shfl butterfly ----
        const int lane = tid - 960;
        float v = -INFINITY; int idx = 0;
        for (int i = lane; i < ND; i += 64) {
            float w = delay_param[i] + gumbel[i];
            if (w > v) { v = w; idx = i; }     // strict >: first occurrence wins
        }
#pragma unroll
        for (int off = 32; off > 0; off >>= 1) {
            float v2 = __shfl_xor(v, off);
            int   i2 = __shfl_xor(idx, off);
            if (v2 > v || (v2 == v && i2 < idx)) { v = v2; idx = i2; }
        }
        if (lane == 0) {
            const int p = idx;
            // rc = tanh(reflection_coeffs); k = resonant_activation(rc, 0) = tanh(rc)
            float k1 = tanhf(tanhf(refl[0]));
            float k2 = tanhf(tanhf(refl[1]));
            float a1 = k1 * (1.0f - k2);
            float a2 = fminf(fmaxf(k2, -0.999f), 0.999f);
            float bound = 0.999f - fabsf(a2);
            a1 = fminf(fmaxf(a1, -bound), bound);
            float fg = feedback_gain[0];
            float g = powf(1.0f / (1.0f + expf(-fg)), 0.45f);
            a1 *= g; a2 *= g;
            const int p2 = (p + 1) % ND;           // jnp.roll(one_hot, 1)
            const int dA = MIN_DELAY_C + p + 1;    // coeff 60+p multiplies y[t-(61+p)]
            const int dB = MIN_DELAY_C + p2 + 1;

            float p1[9], q2[9];
            p1[0] = 1.0f; q2[0] = 1.0f;
            for (int i = 1; i < 9; ++i) { p1[i] = p1[i-1] * a1; q2[i] = q2[i-1] * a2; }
            const float C2[3] = {1.f, 2.f, 1.f};
            const float C4[5] = {1.f, 4.f, 6.f, 4.f, 1.f};
            const float C8[9] = {1.f, 8.f, 28.f, 56.f, 70.f, 56.f, 28.f, 8.f, 1.f};
            // (1 - S):
            s_c1[0] = -a1; s_l1[0] = dA;
            s_c1[1] = -a2; s_l1[1] = dB;
            // S^m = sum_i C(m,i) a1^i a2^(m-i) z^-(i*dA + (m-i)*dB)
            for (int i = 0; i < 3; ++i) { s_c2[i] = C2[i] * p1[i] * q2[2-i]; s_l2[i] = i*dA + (2-i)*dB; }
            for (int i = 0; i < 5; ++i) { s_c4[i] = C4[i] * p1[i] * q2[4-i]; s_l4[i] = i*dA + (4-i)*dB; }
            for (int i = 0; i < 9; ++i) { s_c8[i] = C8[i] * p1[i] * q2[8-i]; s_l8[i] = i*dA + (8-i)*dB; }
            s_dA = dA; s_dB = dB;
        }
    }
    __syncthreads();   // row loaded + tables ready

    const int t0 = 4 * tid;        // group 0: t0 in [0,4096)   -> masked (all lags <= 3360)
    const int t1 = t0 + GSTRIDE;   // group 1: t1 in [4096,8192) -> unmasked

    // ---- pass 1: bufB = (1 - S) bufA ----
    {
        float c[2]; int l[2];
#pragma unroll
        for (int j = 0; j < 2; ++j) { c[j] = s_c1[j]; l[j] = s_l1[j]; }
        fir_group<2, true >(bufA, bufB, t0, c, l);
        fir_group<2, false>(bufA, bufB, t1, c, l);
    }
    __syncthreads();

    // ---- pass 2: bufA = (1 + S^2) bufB ----
    {
        float c[3]; int l[3];
#pragma unroll
        for (int j = 0; j < 3; ++j) { c[j] = s_c2[j]; l[j] = s_l2[j]; }
        fir_group<3, true >(bufB, bufA, t0, c, l);
        fir_group<3, false>(bufB, bufA, t1, c, l);
    }
    __syncthreads();

    // ---- pass 3: bufB = (1 + S^4) bufA ----
    {
        float c[5]; int l[5];
#pragma unroll
        for (int j = 0; j < 5; ++j) { c[j] = s_c4[j]; l[j] = s_l4[j]; }
        fir_group<5, true >(bufA, bufB, t0, c, l);
        fir_group<5, false>(bufA, bufB, t1, c, l);
    }
    __syncthreads();

    // ---- recurrence: y = w + S^8 y, in-place in bufB; min lag 8*min(dA,dB) >= 488 ----
    {
        float c[9]; int l[9];
#pragma unroll
        for (int j = 0; j < 9; ++j) { c[j] = s_c8[j]; l[j] = s_l8[j]; }
        const int dA = s_dA, dB = s_dB;
        const int dmin = (dA < dB) ? dA : dB;
        const int W = 8 * dmin;    // safe parallel-chunk width, 488..3360
        for (int pos = 0; pos < T_LEN; pos += W) {
            int end = pos + W; if (end > T_LEN) end = T_LEN;
            for (int j = pos + tid; j < end; j += BLOCK) {   // <=4 iterations
                float r[10];
                r[0] = bufB[j];
#pragma unroll
                for (int k = 0; k < 9; ++k) {
                    const int s = j - l[k];                  // all s < pos: prior chunks
                    const float v = bufB[(s >= 0) ? s : 0];  // clamped: always issued
                    r[k + 1] = (s >= 0) ? v : 0.0f;
                }
                float acc = r[0];
#pragma unroll
                for (int k = 0; k < 9; ++k) acc += c[k] * r[k + 1];
                bufB[j] = acc;
            }
            __syncthreads();
        }
    }

    // ---- store (float4) ----
    float4* __restrict__ o4 = (float4*)(out + (size_t)row * T_LEN);
    const float4* b4 = (const float4*)bufB;
    for (int i = tid; i < T_LEN / 4; i += BLOCK) o4[i] = b4[i];
}

extern "C" void kernel_launch(void* const* d_in, const int* in_sizes, int n_in,
                              void* d_out, int out_size, void* d_ws, size_t ws_size,
                              hipStream_t stream) {
    const float* excitation    = (const float*)d_in[0];
    const float* gumbel        = (const float*)d_in[1];
    const float* delay_param   = (const float*)d_in[2];
    const float* feedback_gain = (const float*)d_in[3];
    const float* refl          = (const float*)d_in[4];
    float* out = (float*)d_out;

    ks_resonator_kernel<<<B_ROWS, BLOCK, 0, stream>>>(
        excitation, gumbel, delay_param, feedback_gain, refl, out);
}

// Round 6
// 71.227 us; speedup vs baseline: 1.3792x; 1.0457x over previous
//
#include <hip/hip_runtime.h>
#include <cmath>

#define T_LEN 8192
#define B_ROWS 128
#define ND 360          // MAX_DELAY - MIN_DELAY
#define MIN_DELAY_C 60
#define BLOCK 1024      // 16 waves -> 4 waves/SIMD
#define NCH 8           // strided samples per thread: t = tid + k*BLOCK

// Lag-doubling: 1/(1+S) = (1-S)(1+S^2)(1+S^4) / (1-S^8),  S = a1 z^-dA + a2 z^-dB
// Round 6: conflict-free strided mapping (R5's 4-consecutive mapping was an
// 8-way LDS bank conflict on all lagged reads), centers held in registers
// across passes, identity chunk skipped, global store fused into the chain.

// Processes samples t = tid + (K0+u)*BLOCK, u=0..3. Lagged reads batched
// before FMAs. Center term comes from cen[] (register) and is updated.
template<int NT, int K0, bool MASK, bool STORE>
__device__ __forceinline__ void fir_quad(const float* __restrict__ src,
                                         float* __restrict__ dst,
                                         float* __restrict__ cen,
                                         const float* __restrict__ c,
                                         const int* __restrict__ l,
                                         int tid, float* __restrict__ gout, int W)
{
    float r[4][NT];
#pragma unroll
    for (int u = 0; u < 4; ++u) {
        const int t = tid + (K0 + u) * BLOCK;
#pragma unroll
        for (int j = 0; j < NT; ++j) {
            const int s = t - l[j];
            if (MASK) {
                const float v = src[(s >= 0) ? s : 0];   // clamped: always issued
                r[u][j] = (s >= 0) ? v : 0.0f;
            } else {
                r[u][j] = src[s];
            }
        }
    }
#pragma unroll
    for (int u = 0; u < 4; ++u) {
        const int t = tid + (K0 + u) * BLOCK;
        float acc = cen[K0 + u];
#pragma unroll
        for (int j = 0; j < NT; ++j) acc += c[j] * r[u][j];
        cen[K0 + u] = acc;
        dst[t] = acc;
        if (STORE) { if (t < W) gout[t] = acc; }   // y[0..W) == w[0..W): final
    }
}

__global__ __launch_bounds__(BLOCK) void ks_resonator_kernel(
    const float* __restrict__ excitation,     // (128,1,8192)
    const float* __restrict__ gumbel,         // (360,)
    const float* __restrict__ delay_param,    // (360,)
    const float* __restrict__ feedback_gain,  // (1,)
    const float* __restrict__ refl,           // (2,)
    float* __restrict__ out)                  // (128,1,8192)
{
    __shared__ __align__(16) float bufA[T_LEN];   // 32 KB ping
    __shared__ __align__(16) float bufB[T_LEN];   // 32 KB pong
    __shared__ float s_c1[2], s_c2[3], s_c4[5], s_c8[9];
    __shared__ int   s_l1[2], s_l2[3], s_l4[5], s_l8[9];
    __shared__ int   s_dmin;

    const int tid = threadIdx.x;
    const int row = blockIdx.x;

    if (tid < 960) {
        // ---- waves 0-14: load excitation row into LDS (float4) ----
        const float4* __restrict__ x4 = (const float4*)(excitation + (size_t)row * T_LEN);
        float4* a4 = (float4*)bufA;
        for (int i = tid; i < T_LEN / 4; i += 960) a4[i] = x4[i];
    } else {
        // ---- wave 15: argmax over (delay_param + gumbel) via shfl butterfly ----
        const int lane = tid - 960;
        float v = -INFINITY; int idx = 0;
        for (int i = lane; i < ND; i += 64) {
            float w = delay_param[i] + gumbel[i];
            if (w > v) { v = w; idx = i; }     // strict >: first occurrence wins
        }
#pragma unroll
        for (int off = 32; off > 0; off >>= 1) {
            float v2 = __shfl_xor(v, off);
            int   i2 = __shfl_xor(idx, off);
            if (v2 > v || (v2 == v && i2 < idx)) { v = v2; idx = i2; }
        }
        if (lane == 0) {
            const int p = idx;
            // rc = tanh(reflection_coeffs); k = resonant_activation(rc, 0) = tanh(rc)
            float k1 = tanhf(tanhf(refl[0]));
            float k2 = tanhf(tanhf(refl[1]));
            float a1 = k1 * (1.0f - k2);
            float a2 = fminf(fmaxf(k2, -0.999f), 0.999f);
            float bound = 0.999f - fabsf(a2);
            a1 = fminf(fmaxf(a1, -bound), bound);
            float fg = feedback_gain[0];
            float g = powf(1.0f / (1.0f + expf(-fg)), 0.45f);
            a1 *= g; a2 *= g;
            const int p2 = (p + 1) % ND;           // jnp.roll(one_hot, 1)
            const int dA = MIN_DELAY_C + p + 1;    // coeff 60+p multiplies y[t-(61+p)]
            const int dB = MIN_DELAY_C + p2 + 1;

            float p1[9], q2[9];
            p1[0] = 1.0f; q2[0] = 1.0f;
            for (int i = 1; i < 9; ++i) { p1[i] = p1[i-1] * a1; q2[i] = q2[i-1] * a2; }
            const float C2[3] = {1.f, 2.f, 1.f};
            const float C4[5] = {1.f, 4.f, 6.f, 4.f, 1.f};
            const float C8[9] = {1.f, 8.f, 28.f, 56.f, 70.f, 56.f, 28.f, 8.f, 1.f};
            // (1 - S):
            s_c1[0] = -a1; s_l1[0] = dA;
            s_c1[1] = -a2; s_l1[1] = dB;
            // S^m = sum_i C(m,i) a1^i a2^(m-i) z^-(i*dA + (m-i)*dB)
            for (int i = 0; i < 3; ++i) { s_c2[i] = C2[i] * p1[i] * q2[2-i]; s_l2[i] = i*dA + (2-i)*dB; }
            for (int i = 0; i < 5; ++i) { s_c4[i] = C4[i] * p1[i] * q2[4-i]; s_l4[i] = i*dA + (4-i)*dB; }
            for (int i = 0; i < 9; ++i) { s_c8[i] = C8[i] * p1[i] * q2[8-i]; s_l8[i] = i*dA + (8-i)*dB; }
            s_dmin = (dA < dB) ? dA : dB;
        }
    }
    __syncthreads();   // row loaded + tables ready

    float* __restrict__ o = out + (size_t)row * T_LEN;
    const int W = 8 * s_dmin;   // safe chain-chunk width, 488..3360; also all S^8 lags >= W

    // ---- centers into registers (conflict-free strided b32) ----
    float cen[NCH];
#pragma unroll
    for (int k = 0; k < NCH; ++k) cen[k] = bufA[tid + k * BLOCK];

    // ---- pass 1: bufB = (1 - S) bufA       (lags <= 420 < 1024: mask k<4 only) ----
    {
        float c[2]; int l[2];
#pragma unroll
        for (int j = 0; j < 2; ++j) { c[j] = s_c1[j]; l[j] = s_l1[j]; }
        fir_quad<2, 0, true , false>(bufA, bufB, cen, c, l, tid, nullptr, 0);
        fir_quad<2, 4, false, false>(bufA, bufB, cen, c, l, tid, nullptr, 0);
    }
    __syncthreads();

    // ---- pass 2: bufA = (1 + S^2) bufB     (lags <= 840 < 1024) ----
    {
        float c[3]; int l[3];
#pragma unroll
        for (int j = 0; j < 3; ++j) { c[j] = s_c2[j]; l[j] = s_l2[j]; }
        fir_quad<3, 0, true , false>(bufB, bufA, cen, c, l, tid, nullptr, 0);
        fir_quad<3, 4, false, false>(bufB, bufA, cen, c, l, tid, nullptr, 0);
    }
    __syncthreads();

    // ---- pass 3: bufB = (1 + S^4) bufA     (lags <= 1680 < 4096); store y[t<W] ----
    {
        float c[5]; int l[5];
#pragma unroll
        for (int j = 0; j < 5; ++j) { c[j] = s_c4[j]; l[j] = s_l4[j]; }
        fir_quad<5, 0, true , true >(bufA, bufB, cen, c, l, tid, o, W);
        fir_quad<5, 4, false, true >(bufA, bufB, cen, c, l, tid, o, W);
    }

    // ---- chain: y = w + S^8 y in bufB; chunk 0 is identity (skipped) ----
    {
        float c[9]; int l[9];
#pragma unroll
        for (int j = 0; j < 9; ++j) { c[j] = s_c8[j]; l[j] = s_l8[j]; }
        for (int pos = W; pos < T_LEN; pos += W) {
            __syncthreads();                         // prior chunk / pass3 visible
            int end = pos + W; if (end > T_LEN) end = T_LEN;
            for (int j = pos + tid; j < end; j += BLOCK) {   // <=4 iters, typ 1
                float r[9];
#pragma unroll
                for (int k = 0; k < 9; ++k) {
                    const int s = j - l[k];                  // all s <= j-W < pos
                    const float v = bufB[(s >= 0) ? s : 0];  // clamped: always issued
                    r[k] = (s >= 0) ? v : 0.0f;
                }
                float acc = bufB[j];
#pragma unroll
                for (int k = 0; k < 9; ++k) acc += c[k] * r[k];
                bufB[j] = acc;
                o[j] = acc;                          // fused final store (coalesced)
            }
        }
    }
}

extern "C" void kernel_launch(void* const* d_in, const int* in_sizes, int n_in,
                              void* d_out, int out_size, void* d_ws, size_t ws_size,
                              hipStream_t stream) {
    const float* excitation    = (const float*)d_in[0];
    const float* gumbel        = (const float*)d_in[1];
    const float* delay_param   = (const float*)d_in[2];
    const float* feedback_gain = (const float*)d_in[3];
    const float* refl          = (const float*)d_in[4];
    float* out = (float*)d_out;

    ks_resonator_kernel<<<B_ROWS, BLOCK, 0, stream>>>(
        excitation, gumbel, delay_param, feedback_gain, refl, out);
}

// Round 7
// 69.744 us; speedup vs baseline: 1.4086x; 1.0213x over previous
//
#include <hip/hip_runtime.h>
#include <cmath>

#define T_LEN 8192
#define B_ROWS 128
#define ND 360          // MAX_DELAY - MIN_DELAY
#define MIN_DELAY_C 60
#define BLOCK 1024      // 16 waves -> 4 waves/SIMD
#define NCH 8           // strided samples per thread: t = tid + k*BLOCK
#define GUARD 3360      // >= max possible lag (8*420); zeroed prefix kills all clamps

// Lag-doubling: 1/(1+S) = (1-S)(1+S^2)(1+S^4) / (1-S^8),  S = a1 z^-dA + a2 z^-dB
// Round 7: (1) raw lgkmcnt-only barriers (no vmcnt drain -> fused global stores
// are free), (2) zeroed guard region replaces every boundary clamp/branch,
// (3) tree-summed chain taps. Strided conflict-free mapping kept from R6.

// lgkm-only barrier: LDS producer->consumer ordering without draining global
// stores (hipcc's __syncthreads inserts s_waitcnt vmcnt(0), a ~300-500 cyc
// store-drain per chain chunk). Memory-clobber asm pins code motion.
#define BAR() do {                                             \
    asm volatile("s_waitcnt lgkmcnt(0)" ::: "memory");         \
    __builtin_amdgcn_s_barrier();                              \
    asm volatile("" ::: "memory");                             \
} while (0)

// FIR quad over samples t = tid + (K0+u)*BLOCK, u=0..3, reading src at t-l[j]
// through the guard (no masking). Center term from cen[] registers.
// STORE: emit final y for t < W (y[0..W) == w[0..W), chain identity chunk).
template<int NT, int K0, bool STORE>
__device__ __forceinline__ void fir_quad(const float* __restrict__ src,
                                         float* __restrict__ dst,
                                         float* __restrict__ cen,
                                         const float* __restrict__ c,
                                         const int* __restrict__ l,
                                         int tid, float* __restrict__ gout, int W)
{
    float r[4][NT];
#pragma unroll
    for (int u = 0; u < 4; ++u) {
        const int t = tid + (K0 + u) * BLOCK;
#pragma unroll
        for (int j = 0; j < NT; ++j) r[u][j] = src[GUARD + t - l[j]];
    }
#pragma unroll
    for (int u = 0; u < 4; ++u) {
        const int t = tid + (K0 + u) * BLOCK;
        float acc = cen[K0 + u];
#pragma unroll
        for (int j = 0; j < NT; ++j) acc += c[j] * r[u][j];
        cen[K0 + u] = acc;
        dst[GUARD + t] = acc;
        if (STORE) { if (t < W) gout[t] = acc; }
    }
}

__global__ __launch_bounds__(BLOCK) void ks_resonator_kernel(
    const float* __restrict__ excitation,     // (128,1,8192)
    const float* __restrict__ gumbel,         // (360,)
    const float* __restrict__ delay_param,    // (360,)
    const float* __restrict__ feedback_gain,  // (1,)
    const float* __restrict__ refl,           // (2,)
    float* __restrict__ out)                  // (128,1,8192)
{
    __shared__ __align__(16) float A[GUARD + T_LEN];   // 46.2 KB ping (+guard)
    __shared__ __align__(16) float B[GUARD + T_LEN];   // 46.2 KB pong (+guard)
    __shared__ float s_c1[2], s_c2[3], s_c4[5], s_c8[9];
    __shared__ int   s_l1[2], s_l2[3], s_l4[5], s_l8[9];
    __shared__ int   s_dmin;

    const int tid = threadIdx.x;
    const int row = blockIdx.x;

    if (tid < 960) {
        // ---- waves 0-14: zero guards + load excitation row (float4) ----
        float4 z4 = make_float4(0.f, 0.f, 0.f, 0.f);
        float4* ag = (float4*)A;
        float4* bg = (float4*)B;
        for (int i = tid; i < GUARD / 4; i += 960) { ag[i] = z4; bg[i] = z4; }
        const float4* __restrict__ x4 = (const float4*)(excitation + (size_t)row * T_LEN);
        float4* ax = (float4*)(A + GUARD);
        for (int i = tid; i < T_LEN / 4; i += 960) ax[i] = x4[i];
    } else {
        // ---- wave 15: argmax over (delay_param + gumbel) via shfl butterfly ----
        const int lane = tid - 960;
        float v = -INFINITY; int idx = 0;
        for (int i = lane; i < ND; i += 64) {
            float w = delay_param[i] + gumbel[i];
            if (w > v) { v = w; idx = i; }     // strict >: first occurrence wins
        }
#pragma unroll
        for (int off = 32; off > 0; off >>= 1) {
            float v2 = __shfl_xor(v, off);
            int   i2 = __shfl_xor(idx, off);
            if (v2 > v || (v2 == v && i2 < idx)) { v = v2; idx = i2; }
        }
        if (lane == 0) {
            const int p = idx;
            // rc = tanh(reflection_coeffs); k = resonant_activation(rc, 0) = tanh(rc)
            float k1 = tanhf(tanhf(refl[0]));
            float k2 = tanhf(tanhf(refl[1]));
            float a1 = k1 * (1.0f - k2);
            float a2 = fminf(fmaxf(k2, -0.999f), 0.999f);
            float bound = 0.999f - fabsf(a2);
            a1 = fminf(fmaxf(a1, -bound), bound);
            float fg = feedback_gain[0];
            float g = powf(1.0f / (1.0f + expf(-fg)), 0.45f);
            a1 *= g; a2 *= g;
            const int p2 = (p + 1) % ND;           // jnp.roll(one_hot, 1)
            const int dA = MIN_DELAY_C + p + 1;    // coeff 60+p multiplies y[t-(61+p)]
            const int dB = MIN_DELAY_C + p2 + 1;

            float p1[9], q2[9];
            p1[0] = 1.0f; q2[0] = 1.0f;
            for (int i = 1; i < 9; ++i) { p1[i] = p1[i-1] * a1; q2[i] = q2[i-1] * a2; }
            const float C2[3] = {1.f, 2.f, 1.f};
            const float C4[5] = {1.f, 4.f, 6.f, 4.f, 1.f};
            const float C8[9] = {1.f, 8.f, 28.f, 56.f, 70.f, 56.f, 28.f, 8.f, 1.f};
            // (1 - S):
            s_c1[0] = -a1; s_l1[0] = dA;
            s_c1[1] = -a2; s_l1[1] = dB;
            // S^m = sum_i C(m,i) a1^i a2^(m-i) z^-(i*dA + (m-i)*dB)
            for (int i = 0; i < 3; ++i) { s_c2[i] = C2[i] * p1[i] * q2[2-i]; s_l2[i] = i*dA + (2-i)*dB; }
            for (int i = 0; i < 5; ++i) { s_c4[i] = C4[i] * p1[i] * q2[4-i]; s_l4[i] = i*dA + (4-i)*dB; }
            for (int i = 0; i < 9; ++i) { s_c8[i] = C8[i] * p1[i] * q2[8-i]; s_l8[i] = i*dA + (8-i)*dB; }
            s_dmin = (dA < dB) ? dA : dB;
        }
    }
    BAR();   // row + guards + tables ready (vm waits folded into data deps)

    float* __restrict__ o = out + (size_t)row * T_LEN;
    const int W = 8 * s_dmin;   // chain chunk width = min S^8 lag, 488..3360

    // ---- centers into registers (conflict-free strided b32) ----
    float cen[NCH];
#pragma unroll
    for (int k = 0; k < NCH; ++k) cen[k] = A[GUARD + tid + k * BLOCK];

    // ---- pass 1: B = (1 - S) A ----
    {
        float c[2]; int l[2];
#pragma unroll
        for (int j = 0; j < 2; ++j) { c[j] = s_c1[j]; l[j] = s_l1[j]; }
        fir_quad<2, 0, false>(A, B, cen, c, l, tid, nullptr, 0);
        fir_quad<2, 4, false>(A, B, cen, c, l, tid, nullptr, 0);
    }
    BAR();

    // ---- pass 2: A = (1 + S^2) B ----
    {
        float c[3]; int l[3];
#pragma unroll
        for (int j = 0; j < 3; ++j) { c[j] = s_c2[j]; l[j] = s_l2[j]; }
        fir_quad<3, 0, false>(B, A, cen, c, l, tid, nullptr, 0);
        fir_quad<3, 4, false>(B, A, cen, c, l, tid, nullptr, 0);
    }
    BAR();

    // ---- pass 3: B = (1 + S^4) A; fused store of y[0..W) = w[0..W) ----
    {
        float c[5]; int l[5];
#pragma unroll
        for (int j = 0; j < 5; ++j) { c[j] = s_c4[j]; l[j] = s_l4[j]; }
        fir_quad<5, 0, true >(A, B, cen, c, l, tid, o, W);
        fir_quad<5, 4, true >(A, B, cen, c, l, tid, o, W);
    }
    BAR();

    // ---- chain: y = w + S^8 y in B (identity chunk skipped); fused stores ----
    {
        float c[9]; int l[9];
#pragma unroll
        for (int j = 0; j < 9; ++j) { c[j] = s_c8[j]; l[j] = s_l8[j]; }
        for (int pos = W; pos < T_LEN; pos += W) {
            int end = pos + W; if (end > T_LEN) end = T_LEN;
            for (int j = pos + tid; j < end; j += BLOCK) {   // <=4 iters, typ 1
                const int base = GUARD + j;
                float r[9];
#pragma unroll
                for (int k = 0; k < 9; ++k) r[k] = B[base - l[k]];  // unguarded
                const float w0 = B[base];
                // tree sum: short dependent-FMA path
                float t0 = c[0] * r[0] + c[1] * r[1];
                float t1 = c[2] * r[2] + c[3] * r[3];
                float t2 = c[4] * r[4] + c[5] * r[5];
                float t3 = c[6] * r[6] + c[7] * r[7];
                float t4 = c[8] * r[8] + w0;
                float y  = (t0 + t1) + (t2 + t3) + t4;
                B[base] = y;
                o[j] = y;                    // fire-and-forget (no vmcnt drain)
            }
            BAR();                           // lgkm-only: stores stay in flight
        }
    }
}

extern "C" void kernel_launch(void* const* d_in, const int* in_sizes, int n_in,
                              void* d_out, int out_size, void* d_ws, size_t ws_size,
                              hipStream_t stream) {
    const float* excitation    = (const float*)d_in[0];
    const float* gumbel        = (const float*)d_in[1];
    const float* delay_param   = (const float*)d_in[2];
    const float* feedback_gain = (const float*)d_in[3];
    const float* refl          = (const float*)d_in[4];
    float* out = (float*)d_out;

    ks_resonator_kernel<<<B_ROWS, BLOCK, 0, stream>>>(
        excitation, gumbel, delay_param, feedback_gain, refl, out);
}